// Round 2
// baseline (418.699 us; speedup 1.0000x reference)
//
#include <hip/hip_runtime.h>
#include <hip/hip_bf16.h>

typedef __hip_bfloat16 bf16;
typedef __attribute__((ext_vector_type(8))) short short8;
typedef __attribute__((ext_vector_type(4))) float floatx4;

__device__ __forceinline__ float cvt(float v){ return v; }
__device__ __forceinline__ float cvt(bf16 v){ return __bfloat162float(v); }
__device__ __forceinline__ unsigned short f2bu(float f){
    union { float f; unsigned u; } uf; uf.f = f;
    unsigned u = uf.u;
    return (unsigned short)((u + 0x7FFFu + ((u>>16)&1u)) >> 16);   // RNE
}
__device__ __forceinline__ float bu2f(unsigned short b){
    union { unsigned u; float f; } uf; uf.u = ((unsigned)b)<<16; return uf.f;
}
__device__ __forceinline__ floatx4 mfma16(short8 a, short8 b, floatx4 c){
    return __builtin_amdgcn_mfma_f32_16x16x32_bf16(a, b, c, 0, 0, 0);
}
// LDS bank-conflict swizzle: row = 32-short (64B) row id, part = 16B block (0..3).
// XOR part with (row>>1)&3 -> 16 consecutive rows cover all 32 banks 2-way (free).
__device__ __forceinline__ int swz8(int row, int part){
    return row*32 + ((part ^ ((row>>1)&3))<<3);
}

// ---- workspace layout (float units) ----
constexpr size_t O_KW    = 0;                        // (8,4096,36) fp32 softmaxed
constexpr size_t O_ENH   = O_KW    + 1179648;        // (8,256,64,64) fp32 NCHW
constexpr size_t O_XBT   = O_ENH   + 8388608;        // bf16 NHWC [8][4096][256] -> 4194304 fl
constexpr size_t O_COMPB = O_XBT   + 4194304;        // bf16 NHWC [8][4096][128] -> 2097152 fl
constexpr size_t O_TB    = O_COMPB + 2097152;        // bf16 NHWC [8][4096][64]  -> 1048576 fl
constexpr size_t O_POOL  = O_TB    + 1048576;        // (8,256)
constexpr size_t O_GATE  = O_POOL  + 2048;           // (8,256)
constexpr size_t O_WKC   = O_GATE  + 2048;           // 128*256 fp32
constexpr size_t O_BKC   = O_WKC   + 32768;          // 128
constexpr size_t O_WKP1  = O_BKC   + 128;            // 64*128*9 fp32
constexpr size_t O_ALPHA = O_WKP1  + 73728;          // 64
constexpr size_t O_BETA  = O_ALPHA + 64;             // 64
constexpr size_t O_WKP2  = O_BETA  + 64;             // 36*64
constexpr size_t O_BKP2  = O_WKP2  + 2304;           // 36 (pad 64)
constexpr size_t O_WDEF  = O_BKP2  + 64;             // 256*64*9 fp32
constexpr size_t O_WG1   = O_WDEF  + 147456;         // 64*256
constexpr size_t O_BG1   = O_WG1   + 16384;          // 64
constexpr size_t O_WG2   = O_BG1   + 64;             // 256*64
constexpr size_t O_BG2   = O_WG2   + 16384;          // 256
constexpr size_t O_FLAG  = O_BG2   + 256;            // 1
constexpr size_t O_WKCB  = (O_FLAG + 1 + 3) & ~(size_t)3;   // bf16 [8kc][128][32] -> 16384 fl
constexpr size_t O_WKP1B = O_WKCB  + 16384;          // bf16 [4ch][9][64][32] -> 36864 fl
constexpr size_t O_WDEFB = O_WKP1B + 36864;          // bf16 [4g][2ch][9][64][32] -> 73728 fl

// ---- kdet: input dtype from Wkc bit patterns (proven: fp32 -> hits>0) ----
__global__ __launch_bounds__(256) void kdet(const unsigned* __restrict__ w, float* flag)
{
    int hits = 0;
    for (int i = threadIdx.x; i < 16384; i += 256){
        unsigned v = w[i];
        hits += (((v >> 7) & 0xFFu) == 0xFFu) ? 1 : 0;
    }
    __shared__ int sh[256];
    sh[threadIdx.x] = hits;
    __syncthreads();
    for (int o = 128; o > 0; o >>= 1){
        if (threadIdx.x < o) sh[threadIdx.x] += sh[threadIdx.x + o];
        __syncthreads();
    }
    if (threadIdx.x == 0) flag[0] = (sh[0] > 0) ? 1.0f : 0.0f;
}

// ---- k0: convert all weights ->fp32, fold BN, zero pooled accumulator ----
template<typename T>
__device__ __forceinline__ void k0_body(
    const T* Wkc, const T* bkc, const T* Wkp1, const T* bkp1,
    const T* g1, const T* be1, const T* m1, const T* v1,
    const T* Wkp2, const T* bkp2, const T* Wdef,
    const T* Wg1, const T* bg1, const T* Wg2, const T* bg2,
    float* ws)
{
    int i = blockIdx.x*256 + threadIdx.x;
    if (i < 32768){ ws[O_WKC+i] = cvt(Wkc[i]); return; }  i -= 32768;
    if (i < 128)  { ws[O_BKC+i] = cvt(bkc[i]); return; }  i -= 128;
    if (i < 73728){ ws[O_WKP1+i]= cvt(Wkp1[i]); return; } i -= 73728;
    if (i < 64){
        float a = cvt(g1[i]) / sqrtf(cvt(v1[i]) + 1e-5f);
        ws[O_ALPHA+i] = a;
        ws[O_BETA+i]  = (cvt(bkp1[i]) - cvt(m1[i]))*a + cvt(be1[i]);
        return;
    } i -= 64;
    if (i < 2304) { ws[O_WKP2+i] = cvt(Wkp2[i]); return; } i -= 2304;
    if (i < 36)   { ws[O_BKP2+i] = cvt(bkp2[i]); return; } i -= 36;
    if (i < 147456){ ws[O_WDEF+i]= cvt(Wdef[i]); return; } i -= 147456;
    if (i < 16384){ ws[O_WG1+i]  = cvt(Wg1[i]); return; }  i -= 16384;
    if (i < 64)   { ws[O_BG1+i]  = cvt(bg1[i]); return; }  i -= 64;
    if (i < 16384){ ws[O_WG2+i]  = cvt(Wg2[i]); return; }  i -= 16384;
    if (i < 256)  { ws[O_BG2+i]  = cvt(bg2[i]); return; }  i -= 256;
    if (i < 2048) { ws[O_POOL+i] = 0.f; return; }          // pooled accum zero
}

__global__ __launch_bounds__(256) void k0_prep(
    const void* Wkc, const void* bkc, const void* Wkp1, const void* bkp1,
    const void* g1, const void* be1, const void* m1, const void* v1,
    const void* Wkp2, const void* bkp2, const void* Wdef,
    const void* Wg1, const void* bg1, const void* Wg2, const void* bg2,
    float* ws)
{
    if (ws[O_FLAG] > 0.5f)
        k0_body<float>((const float*)Wkc,(const float*)bkc,(const float*)Wkp1,(const float*)bkp1,
                       (const float*)g1,(const float*)be1,(const float*)m1,(const float*)v1,
                       (const float*)Wkp2,(const float*)bkp2,(const float*)Wdef,
                       (const float*)Wg1,(const float*)bg1,(const float*)Wg2,(const float*)bg2, ws);
    else
        k0_body<bf16>((const bf16*)Wkc,(const bf16*)bkc,(const bf16*)Wkp1,(const bf16*)bkp1,
                      (const bf16*)g1,(const bf16*)be1,(const bf16*)m1,(const bf16*)v1,
                      (const bf16*)Wkp2,(const bf16*)bkp2,(const bf16*)Wdef,
                      (const bf16*)Wg1,(const bf16*)bg1,(const bf16*)Wg2,(const bf16*)bg2, ws);
}

// ---- k0b: pack MFMA bf16 weight layouts from fp32 ws ----
__global__ __launch_bounds__(256) void k0b_pack(float* ws)
{
    unsigned short* wkcb  = (unsigned short*)(ws + O_WKCB);
    unsigned short* wkp1b = (unsigned short*)(ws + O_WKP1B);
    unsigned short* wdefb = (unsigned short*)(ws + O_WDEFB);
    int i = blockIdx.x*256 + threadIdx.x;
    if (i < 32768){                      // [kc8][cout128][cil32] <- Wkc[cout][256]
        int kc = i>>12, cout = (i>>5)&127, cil = i&31;
        wkcb[i] = f2bu(ws[O_WKC + (size_t)cout*256 + kc*32 + cil]);
        return;
    } i -= 32768;
    if (i < 73728){                      // [ch4][kp9][cout64][cil32] <- Wkp1[cout][128][9]
        int ch = i/18432, r = i - ch*18432;
        int kp = r>>11, cout = (r>>5)&63, cil = r&31;
        wkp1b[i] = f2bu(ws[O_WKP1 + ((size_t)cout*128 + ch*32 + cil)*9 + kp]);
        return;
    } i -= 73728;
    if (i < 147456){                     // [g4][ch2][kp9][cout64][cil32] <- Wdef[g*64+cout][64][9]
        int g = i/36864, r1 = i - g*36864;
        int ch = r1/18432, r2 = r1 - ch*18432;
        int kp = r2>>11, cout = (r2>>5)&63, cil = r2&31;
        wdefb[i] = f2bu(ws[O_WDEF + (((size_t)(g*64+cout))*64 + ch*32 + cil)*9 + kp]);
    }
}

// ---- xcvt: x (NCHW fp32/bf16) -> xbt (NHWC bf16) via LDS transpose ----
template<typename T>
__device__ __forceinline__ void xcvt_body(const T* __restrict__ x, unsigned short* __restrict__ xbt,
                                          float* lT)
{
    const int b = blockIdx.y;
    const int ci0 = (blockIdx.x & 3) * 64;
    const int pos0 = (blockIdx.x >> 2) * 64;
    const int lane = threadIdx.x & 63;
    const int wrow = threadIdx.x >> 6;
    for (int i = wrow; i < 64; i += 4)
        lT[i*65 + lane] = cvt(x[((size_t)(b*256 + ci0 + i))*4096 + pos0 + lane]);
    __syncthreads();
    // packed dword writes: unit u -> pos pr (0..63), ci pair pc (0..31)
    for (int u = threadIdx.x; u < 2048; u += 256){
        const int pr = u >> 5, pc = u & 31;
        unsigned lo = f2bu(lT[(2*pc)*65 + pr]);
        unsigned hi = f2bu(lT[(2*pc+1)*65 + pr]);
        *(unsigned*)&xbt[((size_t)(b*4096) + pos0 + pr)*256 + ci0 + 2*pc] = lo | (hi<<16);
    }
}

__global__ __launch_bounds__(256) void xcvt(const void* x, unsigned short* xbt, const float* flag)
{
    __shared__ float lT[64*65];
    if (*flag > 0.5f) xcvt_body<float>((const float*)x, xbt, lT);
    else              xcvt_body<bf16>((const bf16*)x, xbt, lT);
}

// ---- k1: 1x1 conv as MFMA GEMM: [128 cout] x [256 ci] x [pos] -> compb NHWC bf16 ----
__global__ __launch_bounds__(256) void k1_mfma(
    const unsigned short* __restrict__ xbt, const unsigned short* __restrict__ wb,
    const float* __restrict__ bias, unsigned short* __restrict__ compb)
{
    __shared__ __align__(16) short lA[128*32];
    __shared__ __align__(16) short lB[128*32];
    const int b = blockIdx.y, pos0 = blockIdx.x*128;
    const int tid = threadIdx.x;
    const int wave = tid>>6, lane = tid&63, q = lane>>4, r16 = lane&15;
    const int mh = (wave&1)*64, nh = (wave>>1)*64;
    floatx4 zero = {0.f,0.f,0.f,0.f};
    floatx4 acc[4][4];
    #pragma unroll
    for (int m=0;m<4;m++){ acc[m][0]=zero; acc[m][1]=zero; acc[m][2]=zero; acc[m][3]=zero; }

    for (int kc=0;kc<8;kc++){
        __syncthreads();
        {   // stage A (weights): contiguous 4096 shorts, swizzled rows
            const short8* s = (const short8*)(wb + kc*4096);
            const int u0 = tid, u1 = tid + 256;
            *(short8*)&lA[swz8(u0>>2, u0&3)] = s[u0];
            *(short8*)&lA[swz8(u1>>2, u1&3)] = s[u1];
        }
        {   // stage B (x): [pos128][ci32] — vector 16B units, swizzled
            #pragma unroll
            for (int k=0;k<2;k++){
                const int u = tid + k*256;
                const int p = u>>2, part = u&3;
                *(short8*)&lB[swz8(p, part)] =
                    *(const short8*)(xbt + ((size_t)(b*4096)+pos0+p)*256 + kc*32 + part*8);
            }
        }
        __syncthreads();
        short8 af[4], bfr[4];
        #pragma unroll
        for (int mt=0;mt<4;mt++) af[mt]  = *(const short8*)&lA[swz8(mh + mt*16 + r16, q)];
        #pragma unroll
        for (int nt=0;nt<4;nt++) bfr[nt] = *(const short8*)&lB[swz8(nh + nt*16 + r16, q)];
        #pragma unroll
        for (int mt=0;mt<4;mt++)
            #pragma unroll
            for (int nt=0;nt<4;nt++)
                acc[mt][nt] = mfma16(af[mt], bfr[nt], acc[mt][nt]);
    }
    #pragma unroll
    for (int mt=0;mt<4;mt++){
        const int cb = mh + mt*16 + q*4;
        const float b0=bias[cb], b1=bias[cb+1], b2=bias[cb+2], b3=bias[cb+3];
        #pragma unroll
        for (int nt=0;nt<4;nt++){
            const int pos = pos0 + nh + nt*16 + r16;
            floatx4 v = acc[mt][nt];
            uint2 pk;
            pk.x = (unsigned)f2bu(v.x+b0) | ((unsigned)f2bu(v.y+b1)<<16);
            pk.y = (unsigned)f2bu(v.z+b2) | ((unsigned)f2bu(v.w+b3)<<16);
            *(uint2*)(compb + ((size_t)(b*4096)+pos)*128 + cb) = pk;
        }
    }
}

// ---- merged 3x3 convs as MFMA 9-shift GEMM.
// z=0: kernel-predictor conv (src=compb, CITOT=128, CICH=4) -> BN+SiLU -> tb (bf16 NHWC[64])
// z=1..4: grouped deform conv g=z-1 (src=xbt, CITOT=256, CICH=2) -> enh fp32 NCHW
__global__ __launch_bounds__(256) void conv3x3_all(
    const unsigned short* __restrict__ xbt, const unsigned short* __restrict__ compb,
    const unsigned short* __restrict__ wkp1b, const unsigned short* __restrict__ wdefb,
    const float* __restrict__ alpha, const float* __restrict__ beta,
    unsigned short* __restrict__ tb, float* __restrict__ enh)
{
    __shared__ __align__(16) short lX[6*66*32];   // [r][c][ci] spatial-padded, swizzled
    __shared__ __align__(16) short lW[9*64*32];   // [kp][cout][ci], swizzled
    const int row0 = blockIdx.x*4, b = blockIdx.y, z = blockIdx.z;
    const bool isKP = (z == 0);
    const int g = isKP ? 0 : (z-1);
    const int CICH  = isKP ? 4 : 2;
    const int CITOT = isKP ? 128 : 256;
    const int cibase = g*64;                       // 0 for kp branch
    const unsigned short* src  = isKP ? compb : xbt;
    const unsigned short* wsrc = isKP ? wkp1b : (wdefb + (size_t)g*36864);
    const int tid = threadIdx.x;
    const int wave = tid>>6, lane = tid&63, q = lane>>4, r16 = lane&15;
    floatx4 zero = {0.f,0.f,0.f,0.f};
    floatx4 acc[4][4];
    #pragma unroll
    for (int m=0;m<4;m++){ acc[m][0]=zero; acc[m][1]=zero; acc[m][2]=zero; acc[m][3]=zero; }

    // zero lX once (borders + out-of-range rows stay zero through all ch)
    {
        short8 zz = {0,0,0,0,0,0,0,0};
        short8* d = (short8*)lX;
        for (int i = tid; i < 1584; i += 256) d[i] = zz;
    }

    for (int ch = 0; ch < CICH; ch++){
        __syncthreads();
        {   // stage W chunk: contiguous 18432 shorts (2304 x 16B), swizzled
            const short8* s = (const short8*)(wsrc + ch*18432);
            #pragma unroll
            for (int i=0;i<9;i++){
                const int u = tid + i*256;
                *(short8*)&lW[swz8(u>>2, u&3)] = s[u];
            }
        }
        {   // stage X interior: row r valid cols 0..63 -> lX cols 1..64, swizzled
            const int gc = tid>>2, part = tid&3;
            #pragma unroll
            for (int r=0;r<6;r++){
                const int gr = row0 - 1 + r;
                if ((unsigned)gr < 64u){
                    const unsigned short* sp = src +
                        ((size_t)(b*4096) + gr*64 + gc)*CITOT + cibase + ch*32 + part*8;
                    *(short8*)&lX[swz8(r*66 + 1 + gc, part)] = *(const short8*)sp;
                }
            }
        }
        __syncthreads();
        #pragma unroll
        for (int kp=0; kp<9; kp++){
            const int dr = kp/3, dc = kp - dr*3;
            short8 af[4], bfr[4];
            #pragma unroll
            for (int mt=0;mt<4;mt++)
                af[mt] = *(const short8*)&lW[swz8(kp*64 + mt*16 + r16, q)];
            #pragma unroll
            for (int nt=0;nt<4;nt++)
                bfr[nt] = *(const short8*)&lX[swz8((wave+dr)*66 + nt*16 + r16 + dc, q)];
            #pragma unroll
            for (int mt=0;mt<4;mt++)
                #pragma unroll
                for (int nt=0;nt<4;nt++)
                    acc[mt][nt] = mfma16(af[mt], bfr[nt], acc[mt][nt]);
        }
    }
    const int orow = row0 + wave;
    if (isKP){
        #pragma unroll
        for (int mt=0;mt<4;mt++){
            const int cb = mt*16 + q*4;
            const float a0=alpha[cb],a1=alpha[cb+1],a2=alpha[cb+2],a3=alpha[cb+3];
            const float e0=beta[cb],e1=beta[cb+1],e2=beta[cb+2],e3=beta[cb+3];
            #pragma unroll
            for (int nt=0;nt<4;nt++){
                const int pos = orow*64 + nt*16 + r16;
                floatx4 v = acc[mt][nt];
                float z0=v.x*a0+e0, z1=v.y*a1+e1, z2=v.z*a2+e2, z3=v.w*a3+e3;
                z0 = z0/(1.f+expf(-z0)); z1 = z1/(1.f+expf(-z1));
                z2 = z2/(1.f+expf(-z2)); z3 = z3/(1.f+expf(-z3));
                uint2 pk;
                pk.x = (unsigned)f2bu(z0) | ((unsigned)f2bu(z1)<<16);
                pk.y = (unsigned)f2bu(z2) | ((unsigned)f2bu(z3)<<16);
                *(uint2*)(tb + ((size_t)(b*4096)+pos)*64 + cb) = pk;
            }
        }
    } else {
        #pragma unroll
        for (int mt=0;mt<4;mt++){
            #pragma unroll
            for (int nt=0;nt<4;nt++){
                const int pos = orow*64 + nt*16 + r16;
                floatx4 v = acc[mt][nt];
                float* op = enh + ((size_t)(b*256) + g*64 + mt*16 + q*4)*4096 + pos;
                op[0]=v.x; op[4096]=v.y; op[8192]=v.z; op[12288]=v.w;
            }
        }
    }
}

// ---- k3: 1x1 conv t(64)->36 + softmax over groups of 9 (NHWC bf16 input) ----
__global__ __launch_bounds__(128) void k3_kpred(
    const unsigned short* __restrict__ tb, const float* __restrict__ W,
    const float* __restrict__ bias, float* __restrict__ kw)
{
    __shared__ float wl[2304];
    __shared__ float bl[36];
    for (int i=threadIdx.x;i<2304;i+=128) wl[i]=W[i];
    if (threadIdx.x<36) bl[threadIdx.x]=bias[threadIdx.x];
    __syncthreads();
    const int gid = blockIdx.x*128 + threadIdx.x;    // b*4096+pos
    const unsigned short* tp = tb + (size_t)gid*64;
    float acc[36];
    #pragma unroll
    for (int o=0;o<36;o++) acc[o]=bl[o];
    #pragma unroll
    for (int c8=0;c8<8;c8++){
        uint4 pk = *(const uint4*)(tp + c8*8);
        unsigned u[4] = {pk.x, pk.y, pk.z, pk.w};
        float f[8];
        #pragma unroll
        for (int j=0;j<4;j++){
            f[2*j]   = bu2f((unsigned short)(u[j]&0xFFFFu));
            f[2*j+1] = bu2f((unsigned short)(u[j]>>16));
        }
        #pragma unroll
        for (int jj=0;jj<8;jj++){
            const int ci = c8*8+jj;
            #pragma unroll
            for (int o=0;o<36;o++) acc[o] += f[jj]*wl[o*64+ci];
        }
    }
    float* op = kw + (size_t)gid*36;
    #pragma unroll
    for (int s=0;s<4;s++){
        float mx = acc[s*9];
        #pragma unroll
        for (int k=1;k<9;k++) mx = fmaxf(mx, acc[s*9+k]);
        float e[9]; float sum=0.f;
        #pragma unroll
        for (int k=0;k<9;k++){ e[k]=expf(acc[s*9+k]-mx); sum+=e[k]; }
        float inv = 1.f/sum;
        #pragma unroll
        for (int k=0;k<9;k++) op[s*9+k] = e[k]*inv;
    }
}

// ---- k5: reassembly + bilinear upsample add -> out (fp32), fused spatial-sum ----
// stencil via shfl (lane = wi), pool partials in registers, one reduce at end
template<typename T>
__device__ __forceinline__ void k5_body(
    const T* __restrict__ x, const float* __restrict__ kw,
    const float* __restrict__ enh, float* __restrict__ out,
    float* __restrict__ pooled, float* kwl)
{
    const int hi = blockIdx.x & 63;
    const int b  = blockIdx.x >> 6;
    const int c0 = blockIdx.y * 64;
    for (int i=threadIdx.x;i<2304;i+=256){
        int wi = i/36, r = i - wi*36;
        kwl[wi*37+r] = kw[((size_t)(b*4096 + hi*64 + wi))*36 + r];
    }
    __syncthreads();
    const int wi = threadIdx.x & 63;
    const int cl = threadIdx.x >> 6;
    float kreg[36];
    #pragma unroll
    for (int r=0;r<36;r++) kreg[r] = kwl[wi*37+r];

    const bool vx0 = wi>0, vx2 = wi<63;
    const bool vy0 = hi>0, vy2 = hi<63;
    const int rm = vy0? hi-1 : 0;
    const int rp = vy2? hi+1 : 63;
    const int par = wi&1;
    const int mA = wi>>1, mB = 32+mA;
    float wc0, wc1; int a0,a1,b0c,b1c;
    if (par==0){ wc0=0.25f; wc1=0.75f; a0=(mA>0)?mA-1:0; a1=mA;   b0c=mB-1; b1c=mB; }
    else       { wc0=0.75f; wc1=0.25f; a0=mA;            a1=mA+1; b0c=mB;   b1c=(mB<63)?mB+1:63; }
    const int y0 = hi*2;

    float psum[16];
    #pragma unroll
    for (int i=0;i<16;i++){
        const int c = c0 + cl + 4*i;
        const T* xc = x + ((size_t)(b*256)+c)*4096;
        // 3 coalesced row loads; horizontal neighbors via shfl (lane = wi)
        float xm = vy0 ? cvt(xc[(hi-1)*64+wi]) : 0.f;
        float x0v =       cvt(xc[ hi   *64+wi]);
        float xp = vy2 ? cvt(xc[(hi+1)*64+wi]) : 0.f;
        float lm = __shfl_up(xm, 1, 64),  rmv = __shfl_down(xm, 1, 64);
        float l0 = __shfl_up(x0v, 1, 64), r0v = __shfl_down(x0v, 1, 64);
        float lp = __shfl_up(xp, 1, 64),  rpv = __shfl_down(xp, 1, 64);
        float v0 = vx0 ? lm : 0.f,  v2 = vx2 ? rmv : 0.f;
        float v3 = vx0 ? l0 : 0.f,  v5 = vx2 ? r0v : 0.f;
        float v6 = vx0 ? lp : 0.f,  v8 = vx2 ? rpv : 0.f;
        float ko[4];
        #pragma unroll
        for (int s=0;s<4;s++){
            float a = v0*kreg[s*9+0] + xm *kreg[s*9+1] + v2*kreg[s*9+2]
                    + v3*kreg[s*9+3] + x0v*kreg[s*9+4] + v5*kreg[s*9+5]
                    + v6*kreg[s*9+6] + xp *kreg[s*9+7] + v8*kreg[s*9+8];
            ko[s]=a;
        }
        const float* ec = enh + ((size_t)(b*256)+c)*4096;
        const float* er0 = ec + rm*64;
        const float* er1 = ec + hi*64;
        const float* er2 = ec + rp*64;
        float uA0 = wc0*er0[a0]+wc1*er0[a1];
        float uB0 = wc0*er0[b0c]+wc1*er0[b1c];
        float uA1 = wc0*er1[a0]+wc1*er1[a1];
        float uB1 = wc0*er1[b0c]+wc1*er1[b1c];
        float uA2 = wc0*er2[a0]+wc1*er2[a1];
        float uB2 = wc0*er2[b0c]+wc1*er2[b1c];
        float up00 = 0.25f*uA0 + 0.75f*uA1;
        float up01 = 0.25f*uB0 + 0.75f*uB1;
        float up10 = 0.75f*uA1 + 0.25f*uA2;
        float up11 = 0.75f*uB1 + 0.25f*uB2;
        float o00 = ko[0]+up00, o01 = ko[1]+up01, o10 = ko[2]+up10, o11 = ko[3]+up11;
        float* o = out + (((size_t)(b*256)+c)*128 + y0)*128;
        o[wi]      = o00;
        o[64+wi]   = o01;
        o[128+wi]  = o10;
        o[192+wi]  = o11;
        psum[i] = (o00+o01) + (o10+o11);
    }
    // 16 independent wave reductions (ILP-friendly), then 16 atomics from lane 0
    #pragma unroll
    for (int i=0;i<16;i++){
        float ps = psum[i];
        ps += __shfl_down(ps,32,64); ps += __shfl_down(ps,16,64);
        ps += __shfl_down(ps, 8,64); ps += __shfl_down(ps, 4,64);
        ps += __shfl_down(ps, 2,64); ps += __shfl_down(ps, 1,64);
        psum[i] = ps;
    }
    if (wi==0){
        #pragma unroll
        for (int i=0;i<16;i++)
            atomicAdd(&pooled[b*256 + c0 + cl + 4*i], psum[i]);
    }
}

__global__ __launch_bounds__(256) void k5_fuse(
    const void* x, const float* kw, const float* enh, float* out,
    float* pooled, const float* flag)
{
    __shared__ float kwl[64*37];
    if (*flag > 0.5f) k5_body<float>((const float*)x, kw, enh, out, pooled, kwl);
    else              k5_body<bf16>((const bf16*)x, kw, enh, out, pooled, kwl);
}

// ---- k7: SE gate (pooled holds spatial SUM; scale by 1/16384) ----
__global__ __launch_bounds__(256) void k7_gate(
    const float* __restrict__ pooled,
    const float* __restrict__ Wg1, const float* __restrict__ bg1,
    const float* __restrict__ Wg2, const float* __restrict__ bg2,
    float* __restrict__ gate)
{
    const int b = blockIdx.x;
    __shared__ float pl[256];
    __shared__ float hid[64];
    pl[threadIdx.x] = pooled[b*256+threadIdx.x] * (1.f/16384.f);
    __syncthreads();
    if (threadIdx.x < 64){
        float a = bg1[threadIdx.x];
        const float* w = Wg1 + (size_t)threadIdx.x*256;
        for (int c=0;c<256;c++) a += w[c]*pl[c];
        hid[threadIdx.x] = a/(1.f+expf(-a));
    }
    __syncthreads();
    float a = bg2[threadIdx.x];
    const float* w = Wg2 + (size_t)threadIdx.x*64;
    for (int j=0;j<64;j++) a += w[j]*hid[j];
    gate[b*256+threadIdx.x] = 1.f/(1.f+expf(-a));
}

// ---- k8: out *= gate ----
__global__ __launch_bounds__(256) void k8_scale(
    float* __restrict__ out, const float* __restrict__ gate)
{
    const size_t gid = (size_t)blockIdx.x*256 + threadIdx.x;
    const float g = gate[gid>>12];
    float4* p = (float4*)out;
    float4 v = p[gid];
    v.x*=g; v.y*=g; v.z*=g; v.w*=g;
    p[gid] = v;
}

extern "C" void kernel_launch(void* const* d_in, const int* in_sizes, int n_in,
                              void* d_out, int out_size, void* d_ws, size_t ws_size,
                              hipStream_t stream)
{
    float* ws = (float*)d_ws;
    float* out = (float*)d_out;
    unsigned short* xbt   = (unsigned short*)(ws + O_XBT);
    unsigned short* compb = (unsigned short*)(ws + O_COMPB);
    unsigned short* tb    = (unsigned short*)(ws + O_TB);
    unsigned short* wkcb  = (unsigned short*)(ws + O_WKCB);
    unsigned short* wkp1b = (unsigned short*)(ws + O_WKP1B);
    unsigned short* wdefb = (unsigned short*)(ws + O_WDEFB);

    kdet<<<1, 256, 0, stream>>>((const unsigned*)d_in[1], ws + O_FLAG);
    k0_prep<<<1140, 256, 0, stream>>>(d_in[1],d_in[2],d_in[3],d_in[4],d_in[5],d_in[6],d_in[7],d_in[8],
                                      d_in[9],d_in[10],d_in[11],d_in[12],d_in[13],d_in[14],d_in[15], ws);
    k0b_pack<<<992, 256, 0, stream>>>(ws);
    xcvt<<<dim3(256,8), 256, 0, stream>>>(d_in[0], xbt, ws+O_FLAG);
    k1_mfma<<<dim3(32,8), 256, 0, stream>>>(xbt, wkcb, ws+O_BKC, compb);
    conv3x3_all<<<dim3(16,8,5), 256, 0, stream>>>(xbt, compb, wkp1b, wdefb,
                                                  ws+O_ALPHA, ws+O_BETA, tb, ws+O_ENH);
    k3_kpred<<<256, 128, 0, stream>>>(tb, ws+O_WKP2, ws+O_BKP2, ws+O_KW);
    k5_fuse<<<dim3(512,4), 256, 0, stream>>>(d_in[0], ws+O_KW, ws+O_ENH, out, ws+O_POOL, ws+O_FLAG);
    k7_gate<<<8, 256, 0, stream>>>(ws+O_POOL, ws+O_WG1, ws+O_BG1, ws+O_WG2, ws+O_BG2, ws+O_GATE);
    k8_scale<<<32768, 256, 0, stream>>>(out, ws+O_GATE);
}

// Round 3
// 381.190 us; speedup vs baseline: 1.0984x; 1.0984x over previous
//
#include <hip/hip_runtime.h>
#include <hip/hip_bf16.h>

typedef __hip_bfloat16 bf16;
typedef __attribute__((ext_vector_type(8))) short short8;
typedef __attribute__((ext_vector_type(4))) float floatx4;

__device__ __forceinline__ float cvt(float v){ return v; }
__device__ __forceinline__ float cvt(bf16 v){ return __bfloat162float(v); }
__device__ __forceinline__ unsigned short f2bu(float f){
    union { float f; unsigned u; } uf; uf.f = f;
    unsigned u = uf.u;
    return (unsigned short)((u + 0x7FFFu + ((u>>16)&1u)) >> 16);   // RNE
}
__device__ __forceinline__ float bu2f(unsigned short b){
    union { unsigned u; float f; } uf; uf.u = ((unsigned)b)<<16; return uf.f;
}
__device__ __forceinline__ floatx4 mfma16(short8 a, short8 b, floatx4 c){
    return __builtin_amdgcn_mfma_f32_16x16x32_bf16(a, b, c, 0, 0, 0);
}
// LDS bank-conflict swizzle: row = 32-short (64B) row id, part = 16B block (0..3).
__device__ __forceinline__ int swz8(int row, int part){
    return row*32 + ((part ^ ((row>>1)&3))<<3);
}

// ---- workspace layout (float units) ----
constexpr size_t O_KW    = 0;                        // (8,4096,36) fp32 softmaxed
constexpr size_t O_ENH   = O_KW    + 1179648;        // (8,256,64,64) fp32 NCHW
constexpr size_t O_XBT   = O_ENH   + 8388608;        // bf16 NHWC [8][4096][256] -> 4194304 fl
constexpr size_t O_COMPB = O_XBT   + 4194304;        // bf16 NHWC [8][4096][128] -> 2097152 fl
constexpr size_t O_TB    = O_COMPB + 2097152;        // bf16 NHWC [8][4096][64]  -> 1048576 fl
constexpr size_t O_POOL  = O_TB    + 1048576;        // (8,256)
constexpr size_t O_GATE  = O_POOL  + 2048;           // (8,256)
constexpr size_t O_WKC   = O_GATE  + 2048;           // 128*256 fp32
constexpr size_t O_BKC   = O_WKC   + 32768;          // 128
constexpr size_t O_WKP1  = O_BKC   + 128;            // 64*128*9 fp32
constexpr size_t O_ALPHA = O_WKP1  + 73728;          // 64
constexpr size_t O_BETA  = O_ALPHA + 64;             // 64
constexpr size_t O_WKP2  = O_BETA  + 64;             // 36*64
constexpr size_t O_BKP2  = O_WKP2  + 2304;           // 36 (pad 64)
constexpr size_t O_WDEF  = O_BKP2  + 64;             // 256*64*9 fp32
constexpr size_t O_WG1   = O_WDEF  + 147456;         // 64*256
constexpr size_t O_BG1   = O_WG1   + 16384;          // 64
constexpr size_t O_WG2   = O_BG1   + 64;             // 256*64
constexpr size_t O_BG2   = O_WG2   + 16384;          // 256
constexpr size_t O_FLAG  = O_BG2   + 256;            // 1
constexpr size_t O_WKCB  = (O_FLAG + 1 + 3) & ~(size_t)3;   // bf16 [8kc][128][32] -> 16384 fl
constexpr size_t O_WKP1B = O_WKCB  + 16384;          // bf16 [4ch][9][64][32] -> 36864 fl
constexpr size_t O_WDEFB = O_WKP1B + 36864;          // bf16 [4g][2ch][9][64][32] -> 73728 fl

// ---- kdet: input dtype from Wkc bit patterns (proven: fp32 -> hits>0) ----
__global__ __launch_bounds__(256) void kdet(const unsigned* __restrict__ w, float* flag)
{
    int hits = 0;
    for (int i = threadIdx.x; i < 16384; i += 256){
        unsigned v = w[i];
        hits += (((v >> 7) & 0xFFu) == 0xFFu) ? 1 : 0;
    }
    __shared__ int sh[256];
    sh[threadIdx.x] = hits;
    __syncthreads();
    for (int o = 128; o > 0; o >>= 1){
        if (threadIdx.x < o) sh[threadIdx.x] += sh[threadIdx.x + o];
        __syncthreads();
    }
    if (threadIdx.x == 0) flag[0] = (sh[0] > 0) ? 1.0f : 0.0f;
}

// ---- k0: convert all weights ->fp32, fold BN, zero pooled accumulator ----
template<typename T>
__device__ __forceinline__ void k0_body(
    const T* Wkc, const T* bkc, const T* Wkp1, const T* bkp1,
    const T* g1, const T* be1, const T* m1, const T* v1,
    const T* Wkp2, const T* bkp2, const T* Wdef,
    const T* Wg1, const T* bg1, const T* Wg2, const T* bg2,
    float* ws)
{
    int i = blockIdx.x*256 + threadIdx.x;
    if (i < 32768){ ws[O_WKC+i] = cvt(Wkc[i]); return; }  i -= 32768;
    if (i < 128)  { ws[O_BKC+i] = cvt(bkc[i]); return; }  i -= 128;
    if (i < 73728){ ws[O_WKP1+i]= cvt(Wkp1[i]); return; } i -= 73728;
    if (i < 64){
        float a = cvt(g1[i]) / sqrtf(cvt(v1[i]) + 1e-5f);
        ws[O_ALPHA+i] = a;
        ws[O_BETA+i]  = (cvt(bkp1[i]) - cvt(m1[i]))*a + cvt(be1[i]);
        return;
    } i -= 64;
    if (i < 2304) { ws[O_WKP2+i] = cvt(Wkp2[i]); return; } i -= 2304;
    if (i < 36)   { ws[O_BKP2+i] = cvt(bkp2[i]); return; } i -= 36;
    if (i < 147456){ ws[O_WDEF+i]= cvt(Wdef[i]); return; } i -= 147456;
    if (i < 16384){ ws[O_WG1+i]  = cvt(Wg1[i]); return; }  i -= 16384;
    if (i < 64)   { ws[O_BG1+i]  = cvt(bg1[i]); return; }  i -= 64;
    if (i < 16384){ ws[O_WG2+i]  = cvt(Wg2[i]); return; }  i -= 16384;
    if (i < 256)  { ws[O_BG2+i]  = cvt(bg2[i]); return; }  i -= 256;
    if (i < 2048) { ws[O_POOL+i] = 0.f; return; }          // pooled accum zero
}

__global__ __launch_bounds__(256) void k0_prep(
    const void* Wkc, const void* bkc, const void* Wkp1, const void* bkp1,
    const void* g1, const void* be1, const void* m1, const void* v1,
    const void* Wkp2, const void* bkp2, const void* Wdef,
    const void* Wg1, const void* bg1, const void* Wg2, const void* bg2,
    float* ws)
{
    if (ws[O_FLAG] > 0.5f)
        k0_body<float>((const float*)Wkc,(const float*)bkc,(const float*)Wkp1,(const float*)bkp1,
                       (const float*)g1,(const float*)be1,(const float*)m1,(const float*)v1,
                       (const float*)Wkp2,(const float*)bkp2,(const float*)Wdef,
                       (const float*)Wg1,(const float*)bg1,(const float*)Wg2,(const float*)bg2, ws);
    else
        k0_body<bf16>((const bf16*)Wkc,(const bf16*)bkc,(const bf16*)Wkp1,(const bf16*)bkp1,
                      (const bf16*)g1,(const bf16*)be1,(const bf16*)m1,(const bf16*)v1,
                      (const bf16*)Wkp2,(const bf16*)bkp2,(const bf16*)Wdef,
                      (const bf16*)Wg1,(const bf16*)bg1,(const bf16*)Wg2,(const bf16*)bg2, ws);
}

// ---- k0b: pack MFMA bf16 weight layouts from fp32 ws ----
__global__ __launch_bounds__(256) void k0b_pack(float* ws)
{
    unsigned short* wkcb  = (unsigned short*)(ws + O_WKCB);
    unsigned short* wkp1b = (unsigned short*)(ws + O_WKP1B);
    unsigned short* wdefb = (unsigned short*)(ws + O_WDEFB);
    int i = blockIdx.x*256 + threadIdx.x;
    if (i < 32768){                      // [kc8][cout128][cil32] <- Wkc[cout][256]
        int kc = i>>12, cout = (i>>5)&127, cil = i&31;
        wkcb[i] = f2bu(ws[O_WKC + (size_t)cout*256 + kc*32 + cil]);
        return;
    } i -= 32768;
    if (i < 73728){                      // [ch4][kp9][cout64][cil32] <- Wkp1[cout][128][9]
        int ch = i/18432, r = i - ch*18432;
        int kp = r>>11, cout = (r>>5)&63, cil = r&31;
        wkp1b[i] = f2bu(ws[O_WKP1 + ((size_t)cout*128 + ch*32 + cil)*9 + kp]);
        return;
    } i -= 73728;
    if (i < 147456){                     // [g4][ch2][kp9][cout64][cil32] <- Wdef[g*64+cout][64][9]
        int g = i/36864, r1 = i - g*36864;
        int ch = r1/18432, r2 = r1 - ch*18432;
        int kp = r2>>11, cout = (r2>>5)&63, cil = r2&31;
        wdefb[i] = f2bu(ws[O_WDEF + (((size_t)(g*64+cout))*64 + ch*32 + cil)*9 + kp]);
    }
}

// ---- xcvt: x (NCHW fp32/bf16) -> xbt (NHWC bf16) via LDS transpose ----
template<typename T>
__device__ __forceinline__ void xcvt_body(const T* __restrict__ x, unsigned short* __restrict__ xbt,
                                          float* lT)
{
    const int b = blockIdx.y;
    const int ci0 = (blockIdx.x & 3) * 64;
    const int pos0 = (blockIdx.x >> 2) * 64;
    const int lane = threadIdx.x & 63;
    const int wrow = threadIdx.x >> 6;
    for (int i = wrow; i < 64; i += 4)
        lT[i*65 + lane] = cvt(x[((size_t)(b*256 + ci0 + i))*4096 + pos0 + lane]);
    __syncthreads();
    // packed dword writes: unit u -> pos pr (0..63), ci pair pc (0..31)
    for (int u = threadIdx.x; u < 2048; u += 256){
        const int pr = u >> 5, pc = u & 31;
        unsigned lo = f2bu(lT[(2*pc)*65 + pr]);
        unsigned hi = f2bu(lT[(2*pc+1)*65 + pr]);
        *(unsigned*)&xbt[((size_t)(b*4096) + pos0 + pr)*256 + ci0 + 2*pc] = lo | (hi<<16);
    }
}

__global__ __launch_bounds__(256) void xcvt(const void* x, unsigned short* xbt, const float* flag)
{
    __shared__ float lT[64*65];
    if (*flag > 0.5f) xcvt_body<float>((const float*)x, xbt, lT);
    else              xcvt_body<bf16>((const bf16*)x, xbt, lT);
}

// ---- k1: 1x1 conv as MFMA GEMM: [128 cout] x [256 ci] x [pos] -> compb NHWC bf16 ----
__global__ __launch_bounds__(256) void k1_mfma(
    const unsigned short* __restrict__ xbt, const unsigned short* __restrict__ wb,
    const float* __restrict__ bias, unsigned short* __restrict__ compb)
{
    __shared__ __align__(16) short lA[128*32];
    __shared__ __align__(16) short lB[128*32];
    const int b = blockIdx.y, pos0 = blockIdx.x*128;
    const int tid = threadIdx.x;
    const int wave = tid>>6, lane = tid&63, q = lane>>4, r16 = lane&15;
    const int mh = (wave&1)*64, nh = (wave>>1)*64;
    floatx4 zero = {0.f,0.f,0.f,0.f};
    floatx4 acc[4][4];
    #pragma unroll
    for (int m=0;m<4;m++){ acc[m][0]=zero; acc[m][1]=zero; acc[m][2]=zero; acc[m][3]=zero; }

    for (int kc=0;kc<8;kc++){
        __syncthreads();
        {   // stage A (weights): contiguous 4096 shorts, swizzled rows
            const short8* s = (const short8*)(wb + kc*4096);
            const int u0 = tid, u1 = tid + 256;
            *(short8*)&lA[swz8(u0>>2, u0&3)] = s[u0];
            *(short8*)&lA[swz8(u1>>2, u1&3)] = s[u1];
        }
        {   // stage B (x): [pos128][ci32] — vector 16B units, swizzled
            #pragma unroll
            for (int k=0;k<2;k++){
                const int u = tid + k*256;
                const int p = u>>2, part = u&3;
                *(short8*)&lB[swz8(p, part)] =
                    *(const short8*)(xbt + ((size_t)(b*4096)+pos0+p)*256 + kc*32 + part*8);
            }
        }
        __syncthreads();
        short8 af[4], bfr[4];
        #pragma unroll
        for (int mt=0;mt<4;mt++) af[mt]  = *(const short8*)&lA[swz8(mh + mt*16 + r16, q)];
        #pragma unroll
        for (int nt=0;nt<4;nt++) bfr[nt] = *(const short8*)&lB[swz8(nh + nt*16 + r16, q)];
        #pragma unroll
        for (int mt=0;mt<4;mt++)
            #pragma unroll
            for (int nt=0;nt<4;nt++)
                acc[mt][nt] = mfma16(af[mt], bfr[nt], acc[mt][nt]);
    }
    #pragma unroll
    for (int mt=0;mt<4;mt++){
        const int cb = mh + mt*16 + q*4;
        const float b0=bias[cb], b1=bias[cb+1], b2=bias[cb+2], b3=bias[cb+3];
        #pragma unroll
        for (int nt=0;nt<4;nt++){
            const int pos = pos0 + nh + nt*16 + r16;
            floatx4 v = acc[mt][nt];
            uint2 pk;
            pk.x = (unsigned)f2bu(v.x+b0) | ((unsigned)f2bu(v.y+b1)<<16);
            pk.y = (unsigned)f2bu(v.z+b2) | ((unsigned)f2bu(v.w+b3)<<16);
            *(uint2*)(compb + ((size_t)(b*4096)+pos)*128 + cb) = pk;
        }
    }
}

// ---- merged 3x3 convs as MFMA 9-shift GEMM.
// z=0: kernel-predictor conv (src=compb, CITOT=128, CICH=4) -> BN+SiLU -> tb (bf16 NHWC[64])
// z=1..4: grouped deform conv g=z-1 (src=xbt, CITOT=256, CICH=2) -> enh fp32 NCHW
__global__ __launch_bounds__(256) void conv3x3_all(
    const unsigned short* __restrict__ xbt, const unsigned short* __restrict__ compb,
    const unsigned short* __restrict__ wkp1b, const unsigned short* __restrict__ wdefb,
    const float* __restrict__ alpha, const float* __restrict__ beta,
    unsigned short* __restrict__ tb, float* __restrict__ enh)
{
    __shared__ __align__(16) short lX[6*66*32];   // [r][c][ci] spatial-padded, swizzled
    __shared__ __align__(16) short lW[9*64*32];   // [kp][cout][ci], swizzled
    const int row0 = blockIdx.x*4, b = blockIdx.y, z = blockIdx.z;
    const bool isKP = (z == 0);
    const int g = isKP ? 0 : (z-1);
    const int CICH  = isKP ? 4 : 2;
    const int CITOT = isKP ? 128 : 256;
    const int cibase = g*64;                       // 0 for kp branch
    const unsigned short* src  = isKP ? compb : xbt;
    const unsigned short* wsrc = isKP ? wkp1b : (wdefb + (size_t)g*36864);
    const int tid = threadIdx.x;
    const int wave = tid>>6, lane = tid&63, q = lane>>4, r16 = lane&15;
    floatx4 zero = {0.f,0.f,0.f,0.f};
    floatx4 acc[4][4];
    #pragma unroll
    for (int m=0;m<4;m++){ acc[m][0]=zero; acc[m][1]=zero; acc[m][2]=zero; acc[m][3]=zero; }

    // zero lX once (borders + out-of-range rows stay zero through all ch)
    {
        short8 zz = {0,0,0,0,0,0,0,0};
        short8* d = (short8*)lX;
        for (int i = tid; i < 1584; i += 256) d[i] = zz;
    }

    for (int ch = 0; ch < CICH; ch++){
        __syncthreads();
        {   // stage W chunk: contiguous 18432 shorts (2304 x 16B), swizzled
            const short8* s = (const short8*)(wsrc + ch*18432);
            #pragma unroll
            for (int i=0;i<9;i++){
                const int u = tid + i*256;
                *(short8*)&lW[swz8(u>>2, u&3)] = s[u];
            }
        }
        {   // stage X interior: row r valid cols 0..63 -> lX cols 1..64, swizzled
            const int gc = tid>>2, part = tid&3;
            #pragma unroll
            for (int r=0;r<6;r++){
                const int gr = row0 - 1 + r;
                if ((unsigned)gr < 64u){
                    const unsigned short* sp = src +
                        ((size_t)(b*4096) + gr*64 + gc)*CITOT + cibase + ch*32 + part*8;
                    *(short8*)&lX[swz8(r*66 + 1 + gc, part)] = *(const short8*)sp;
                }
            }
        }
        __syncthreads();
        #pragma unroll
        for (int kp=0; kp<9; kp++){
            const int dr = kp/3, dc = kp - dr*3;
            short8 af[4], bfr[4];
            #pragma unroll
            for (int mt=0;mt<4;mt++)
                af[mt] = *(const short8*)&lW[swz8(kp*64 + mt*16 + r16, q)];
            #pragma unroll
            for (int nt=0;nt<4;nt++)
                bfr[nt] = *(const short8*)&lX[swz8((wave+dr)*66 + nt*16 + r16 + dc, q)];
            #pragma unroll
            for (int mt=0;mt<4;mt++)
                #pragma unroll
                for (int nt=0;nt<4;nt++)
                    acc[mt][nt] = mfma16(af[mt], bfr[nt], acc[mt][nt]);
        }
    }
    const int orow = row0 + wave;
    if (isKP){
        #pragma unroll
        for (int mt=0;mt<4;mt++){
            const int cb = mt*16 + q*4;
            const float a0=alpha[cb],a1=alpha[cb+1],a2=alpha[cb+2],a3=alpha[cb+3];
            const float e0=beta[cb],e1=beta[cb+1],e2=beta[cb+2],e3=beta[cb+3];
            #pragma unroll
            for (int nt=0;nt<4;nt++){
                const int pos = orow*64 + nt*16 + r16;
                floatx4 v = acc[mt][nt];
                float z0=v.x*a0+e0, z1=v.y*a1+e1, z2=v.z*a2+e2, z3=v.w*a3+e3;
                z0 = z0/(1.f+expf(-z0)); z1 = z1/(1.f+expf(-z1));
                z2 = z2/(1.f+expf(-z2)); z3 = z3/(1.f+expf(-z3));
                uint2 pk;
                pk.x = (unsigned)f2bu(z0) | ((unsigned)f2bu(z1)<<16);
                pk.y = (unsigned)f2bu(z2) | ((unsigned)f2bu(z3)<<16);
                *(uint2*)(tb + ((size_t)(b*4096)+pos)*64 + cb) = pk;
            }
        }
    } else {
        #pragma unroll
        for (int mt=0;mt<4;mt++){
            #pragma unroll
            for (int nt=0;nt<4;nt++){
                const int pos = orow*64 + nt*16 + r16;
                floatx4 v = acc[mt][nt];
                float* op = enh + ((size_t)(b*256) + g*64 + mt*16 + q*4)*4096 + pos;
                op[0]=v.x; op[4096]=v.y; op[8192]=v.z; op[12288]=v.w;
            }
        }
    }
}

// ---- k3: 1x1 conv t(64)->36 + softmax over groups of 9 (NHWC bf16 input) ----
__global__ __launch_bounds__(128) void k3_kpred(
    const unsigned short* __restrict__ tb, const float* __restrict__ W,
    const float* __restrict__ bias, float* __restrict__ kw)
{
    __shared__ float wl[2304];
    __shared__ float bl[36];
    for (int i=threadIdx.x;i<2304;i+=128) wl[i]=W[i];
    if (threadIdx.x<36) bl[threadIdx.x]=bias[threadIdx.x];
    __syncthreads();
    const int gid = blockIdx.x*128 + threadIdx.x;    // b*4096+pos
    const unsigned short* tp = tb + (size_t)gid*64;
    float acc[36];
    #pragma unroll
    for (int o=0;o<36;o++) acc[o]=bl[o];
    #pragma unroll
    for (int c8=0;c8<8;c8++){
        uint4 pk = *(const uint4*)(tp + c8*8);
        unsigned u[4] = {pk.x, pk.y, pk.z, pk.w};
        float f[8];
        #pragma unroll
        for (int j=0;j<4;j++){
            f[2*j]   = bu2f((unsigned short)(u[j]&0xFFFFu));
            f[2*j+1] = bu2f((unsigned short)(u[j]>>16));
        }
        #pragma unroll
        for (int jj=0;jj<8;jj++){
            const int ci = c8*8+jj;
            #pragma unroll
            for (int o=0;o<36;o++) acc[o] += f[jj]*wl[o*64+ci];
        }
    }
    float* op = kw + (size_t)gid*36;
    #pragma unroll
    for (int s=0;s<4;s++){
        float mx = acc[s*9];
        #pragma unroll
        for (int k=1;k<9;k++) mx = fmaxf(mx, acc[s*9+k]);
        float e[9]; float sum=0.f;
        #pragma unroll
        for (int k=0;k<9;k++){ e[k]=expf(acc[s*9+k]-mx); sum+=e[k]; }
        float inv = 1.f/sum;
        #pragma unroll
        for (int k=0;k<9;k++) op[s*9+k] = e[k]*inv;
    }
}

// ---- k5: reassembly + bilinear upsample add -> out (fp32), fused spatial-sum ----
// round-1 proven form: 9 independent scalar loads, per-iteration reduce+atomic.
// grid y split to 8 (32 channels/block) for more TLP.
template<typename T>
__device__ __forceinline__ void k5_body(
    const T* __restrict__ x, const float* __restrict__ kw,
    const float* __restrict__ enh, float* __restrict__ out,
    float* __restrict__ pooled, float* kwl)
{
    const int hi = blockIdx.x & 63;
    const int b  = blockIdx.x >> 6;
    const int c0 = blockIdx.y * 32;
    for (int i=threadIdx.x;i<2304;i+=256){
        int wi = i/36, r = i - wi*36;
        kwl[wi*37+r] = kw[((size_t)(b*4096 + hi*64 + wi))*36 + r];
    }
    __syncthreads();
    const int wi = threadIdx.x & 63;
    const int cl = threadIdx.x >> 6;
    float kreg[36];
    #pragma unroll
    for (int r=0;r<36;r++) kreg[r] = kwl[wi*37+r];

    const bool vx0 = wi>0, vx2 = wi<63;
    const bool vy0 = hi>0, vy2 = hi<63;
    const int rm = vy0? hi-1 : 0;
    const int rp = vy2? hi+1 : 63;
    const int par = wi&1;
    const int mA = wi>>1, mB = 32+mA;
    float wc0, wc1; int a0,a1,b0c,b1c;
    if (par==0){ wc0=0.25f; wc1=0.75f; a0=(mA>0)?mA-1:0; a1=mA;   b0c=mB-1; b1c=mB; }
    else       { wc0=0.75f; wc1=0.25f; a0=mA;            a1=mA+1; b0c=mB;   b1c=(mB<63)?mB+1:63; }
    const int y0 = hi*2;

    for (int c = c0+cl; c < c0+32; c += 4){
        const T* xc = x + ((size_t)(b*256)+c)*4096;
        float v[9];
        v[0] = (vy0&&vx0)? cvt(xc[(hi-1)*64+wi-1]) : 0.f;
        v[1] = (vy0)     ? cvt(xc[(hi-1)*64+wi  ]) : 0.f;
        v[2] = (vy0&&vx2)? cvt(xc[(hi-1)*64+wi+1]) : 0.f;
        v[3] = (vx0)     ? cvt(xc[ hi   *64+wi-1]) : 0.f;
        v[4] =             cvt(xc[ hi   *64+wi  ]);
        v[5] = (vx2)     ? cvt(xc[ hi   *64+wi+1]) : 0.f;
        v[6] = (vy2&&vx0)? cvt(xc[(hi+1)*64+wi-1]) : 0.f;
        v[7] = (vy2)     ? cvt(xc[(hi+1)*64+wi  ]) : 0.f;
        v[8] = (vy2&&vx2)? cvt(xc[(hi+1)*64+wi+1]) : 0.f;
        float ko[4];
        #pragma unroll
        for (int s=0;s<4;s++){
            float a = 0.f;
            #pragma unroll
            for (int k=0;k<9;k++) a += v[k]*kreg[s*9+k];
            ko[s]=a;
        }
        const float* ec = enh + ((size_t)(b*256)+c)*4096;
        const float* er0 = ec + rm*64;
        const float* er1 = ec + hi*64;
        const float* er2 = ec + rp*64;
        float uA0 = wc0*er0[a0]+wc1*er0[a1];
        float uB0 = wc0*er0[b0c]+wc1*er0[b1c];
        float uA1 = wc0*er1[a0]+wc1*er1[a1];
        float uB1 = wc0*er1[b0c]+wc1*er1[b1c];
        float uA2 = wc0*er2[a0]+wc1*er2[a1];
        float uB2 = wc0*er2[b0c]+wc1*er2[b1c];
        float up00 = 0.25f*uA0 + 0.75f*uA1;
        float up01 = 0.25f*uB0 + 0.75f*uB1;
        float up10 = 0.75f*uA1 + 0.25f*uA2;
        float up11 = 0.75f*uB1 + 0.25f*uB2;
        float o00 = ko[0]+up00, o01 = ko[1]+up01, o10 = ko[2]+up10, o11 = ko[3]+up11;
        float* o = out + (((size_t)(b*256)+c)*128 + y0)*128;
        o[wi]      = o00;
        o[64+wi]   = o01;
        o[128+wi]  = o10;
        o[192+wi]  = o11;
        // fused spatial-sum: wave holds one c; reduce 64 lanes, 1 atomic per (c, hi)
        float ps = (o00+o01) + (o10+o11);
        #pragma unroll
        for (int off=32;off>0;off>>=1) ps += __shfl_down(ps, off, 64);
        if (wi==0) atomicAdd(&pooled[b*256 + c], ps);
    }
}

__global__ __launch_bounds__(256) void k5_fuse(
    const void* x, const float* kw, const float* enh, float* out,
    float* pooled, const float* flag)
{
    __shared__ float kwl[64*37];
    if (*flag > 0.5f) k5_body<float>((const float*)x, kw, enh, out, pooled, kwl);
    else              k5_body<bf16>((const bf16*)x, kw, enh, out, pooled, kwl);
}

// ---- k7: SE gate (pooled holds spatial SUM; scale by 1/16384) ----
__global__ __launch_bounds__(256) void k7_gate(
    const float* __restrict__ pooled,
    const float* __restrict__ Wg1, const float* __restrict__ bg1,
    const float* __restrict__ Wg2, const float* __restrict__ bg2,
    float* __restrict__ gate)
{
    const int b = blockIdx.x;
    __shared__ float pl[256];
    __shared__ float hid[64];
    pl[threadIdx.x] = pooled[b*256+threadIdx.x] * (1.f/16384.f);
    __syncthreads();
    if (threadIdx.x < 64){
        float a = bg1[threadIdx.x];
        const float* w = Wg1 + (size_t)threadIdx.x*256;
        for (int c=0;c<256;c++) a += w[c]*pl[c];
        hid[threadIdx.x] = a/(1.f+expf(-a));
    }
    __syncthreads();
    float a = bg2[threadIdx.x];
    const float* w = Wg2 + (size_t)threadIdx.x*64;
    for (int j=0;j<64;j++) a += w[j]*hid[j];
    gate[b*256+threadIdx.x] = 1.f/(1.f+expf(-a));
}

// ---- k8: out *= gate ----
__global__ __launch_bounds__(256) void k8_scale(
    float* __restrict__ out, const float* __restrict__ gate)
{
    const size_t gid = (size_t)blockIdx.x*256 + threadIdx.x;
    const float g = gate[gid>>12];
    float4* p = (float4*)out;
    float4 v = p[gid];
    v.x*=g; v.y*=g; v.z*=g; v.w*=g;
    p[gid] = v;
}

extern "C" void kernel_launch(void* const* d_in, const int* in_sizes, int n_in,
                              void* d_out, int out_size, void* d_ws, size_t ws_size,
                              hipStream_t stream)
{
    float* ws = (float*)d_ws;
    float* out = (float*)d_out;
    unsigned short* xbt   = (unsigned short*)(ws + O_XBT);
    unsigned short* compb = (unsigned short*)(ws + O_COMPB);
    unsigned short* tb    = (unsigned short*)(ws + O_TB);
    unsigned short* wkcb  = (unsigned short*)(ws + O_WKCB);
    unsigned short* wkp1b = (unsigned short*)(ws + O_WKP1B);
    unsigned short* wdefb = (unsigned short*)(ws + O_WDEFB);

    kdet<<<1, 256, 0, stream>>>((const unsigned*)d_in[1], ws + O_FLAG);
    k0_prep<<<1140, 256, 0, stream>>>(d_in[1],d_in[2],d_in[3],d_in[4],d_in[5],d_in[6],d_in[7],d_in[8],
                                      d_in[9],d_in[10],d_in[11],d_in[12],d_in[13],d_in[14],d_in[15], ws);
    k0b_pack<<<992, 256, 0, stream>>>(ws);
    xcvt<<<dim3(256,8), 256, 0, stream>>>(d_in[0], xbt, ws+O_FLAG);
    k1_mfma<<<dim3(32,8), 256, 0, stream>>>(xbt, wkcb, ws+O_BKC, compb);
    conv3x3_all<<<dim3(16,8,5), 256, 0, stream>>>(xbt, compb, wkp1b, wdefb,
                                                  ws+O_ALPHA, ws+O_BETA, tb, ws+O_ENH);
    k3_kpred<<<256, 128, 0, stream>>>(tb, ws+O_WKP2, ws+O_BKP2, ws+O_KW);
    k5_fuse<<<dim3(512,8), 256, 0, stream>>>(d_in[0], ws+O_KW, ws+O_ENH, out, ws+O_POOL, ws+O_FLAG);
    k7_gate<<<8, 256, 0, stream>>>(ws+O_POOL, ws+O_WG1, ws+O_BG1, ws+O_WG2, ws+O_BG2, ws+O_GATE);
    k8_scale<<<32768, 256, 0, stream>>>(out, ws+O_GATE);
}

// Round 4
// 352.219 us; speedup vs baseline: 1.1887x; 1.0823x over previous
//
#include <hip/hip_runtime.h>
#include <hip/hip_bf16.h>

typedef __hip_bfloat16 bf16;
typedef __attribute__((ext_vector_type(8))) short short8;
typedef __attribute__((ext_vector_type(4))) float floatx4;

__device__ __forceinline__ float cvt(float v){ return v; }
__device__ __forceinline__ float cvt(bf16 v){ return __bfloat162float(v); }
__device__ __forceinline__ unsigned short f2bu(float f){
    union { float f; unsigned u; } uf; uf.f = f;
    unsigned u = uf.u;
    return (unsigned short)((u + 0x7FFFu + ((u>>16)&1u)) >> 16);   // RNE
}
__device__ __forceinline__ float bu2f(unsigned short b){
    union { unsigned u; float f; } uf; uf.u = ((unsigned)b)<<16; return uf.f;
}
__device__ __forceinline__ floatx4 mfma16(short8 a, short8 b, floatx4 c){
    return __builtin_amdgcn_mfma_f32_16x16x32_bf16(a, b, c, 0, 0, 0);
}
// LDS bank-conflict swizzle: row = 32-short (64B) row id, part = 16B block (0..3).
__device__ __forceinline__ int swz8(int row, int part){
    return row*32 + ((part ^ ((row>>1)&3))<<3);
}
// unaligned-safe 4-element load + cvt
template<typename T>
__device__ __forceinline__ void ld4(const T* p, float& o0, float& o1, float& o2, float& o3){
    T t[4]; __builtin_memcpy(t, p, 4*sizeof(T));
    o0=cvt(t[0]); o1=cvt(t[1]); o2=cvt(t[2]); o3=cvt(t[3]);
}
__device__ __forceinline__ void ld2f(const float* p, float& o0, float& o1){
    float t[2]; __builtin_memcpy(t, p, 8);
    o0=t[0]; o1=t[1];
}

// ---- workspace layout (float units) ----
constexpr size_t O_KW    = 0;                        // (8,4096,36) fp32 softmaxed
constexpr size_t O_ENH   = O_KW    + 1179648;        // (8,256,64,64) fp32 NCHW
constexpr size_t O_XBT   = O_ENH   + 8388608;        // bf16 NHWC [8][4096][256] -> 4194304 fl
constexpr size_t O_COMPB = O_XBT   + 4194304;        // bf16 NHWC [8][4096][128] -> 2097152 fl
constexpr size_t O_TB    = O_COMPB + 2097152;        // bf16 NHWC [8][4096][64]  -> 1048576 fl
constexpr size_t O_POOL  = O_TB    + 1048576;        // (8,256)
constexpr size_t O_GATE  = O_POOL  + 2048;           // (8,256)
constexpr size_t O_WKC   = O_GATE  + 2048;           // 128*256 fp32
constexpr size_t O_BKC   = O_WKC   + 32768;          // 128
constexpr size_t O_WKP1  = O_BKC   + 128;            // 64*128*9 fp32
constexpr size_t O_ALPHA = O_WKP1  + 73728;          // 64
constexpr size_t O_BETA  = O_ALPHA + 64;             // 64
constexpr size_t O_WKP2  = O_BETA  + 64;             // 36*64
constexpr size_t O_BKP2  = O_WKP2  + 2304;           // 36 (pad 64)
constexpr size_t O_WDEF  = O_BKP2  + 64;             // 256*64*9 fp32
constexpr size_t O_WG1   = O_WDEF  + 147456;         // 64*256
constexpr size_t O_BG1   = O_WG1   + 16384;          // 64
constexpr size_t O_WG2   = O_BG1   + 64;             // 256*64
constexpr size_t O_BG2   = O_WG2   + 16384;          // 256
constexpr size_t O_FLAG  = O_BG2   + 256;            // 1
constexpr size_t O_WKCB  = (O_FLAG + 1 + 3) & ~(size_t)3;   // bf16 [8kc][128][32] -> 16384 fl
constexpr size_t O_WKP1B = O_WKCB  + 16384;          // bf16 [4ch][9][64][32] -> 36864 fl
constexpr size_t O_WDEFB = O_WKP1B + 36864;          // bf16 [4g][2ch][9][64][32] -> 73728 fl

// ---- kdet: input dtype from Wkc bit patterns (proven: fp32 -> hits>0) ----
__global__ __launch_bounds__(256) void kdet(const unsigned* __restrict__ w, float* flag)
{
    int hits = 0;
    for (int i = threadIdx.x; i < 16384; i += 256){
        unsigned v = w[i];
        hits += (((v >> 7) & 0xFFu) == 0xFFu) ? 1 : 0;
    }
    __shared__ int sh[256];
    sh[threadIdx.x] = hits;
    __syncthreads();
    for (int o = 128; o > 0; o >>= 1){
        if (threadIdx.x < o) sh[threadIdx.x] += sh[threadIdx.x + o];
        __syncthreads();
    }
    if (threadIdx.x == 0) flag[0] = (sh[0] > 0) ? 1.0f : 0.0f;
}

// ---- k0: convert all weights ->fp32, fold BN, zero pooled accumulator ----
template<typename T>
__device__ __forceinline__ void k0_body(
    const T* Wkc, const T* bkc, const T* Wkp1, const T* bkp1,
    const T* g1, const T* be1, const T* m1, const T* v1,
    const T* Wkp2, const T* bkp2, const T* Wdef,
    const T* Wg1, const T* bg1, const T* Wg2, const T* bg2,
    float* ws)
{
    int i = blockIdx.x*256 + threadIdx.x;
    if (i < 32768){ ws[O_WKC+i] = cvt(Wkc[i]); return; }  i -= 32768;
    if (i < 128)  { ws[O_BKC+i] = cvt(bkc[i]); return; }  i -= 128;
    if (i < 73728){ ws[O_WKP1+i]= cvt(Wkp1[i]); return; } i -= 73728;
    if (i < 64){
        float a = cvt(g1[i]) / sqrtf(cvt(v1[i]) + 1e-5f);
        ws[O_ALPHA+i] = a;
        ws[O_BETA+i]  = (cvt(bkp1[i]) - cvt(m1[i]))*a + cvt(be1[i]);
        return;
    } i -= 64;
    if (i < 2304) { ws[O_WKP2+i] = cvt(Wkp2[i]); return; } i -= 2304;
    if (i < 36)   { ws[O_BKP2+i] = cvt(bkp2[i]); return; } i -= 36;
    if (i < 147456){ ws[O_WDEF+i]= cvt(Wdef[i]); return; } i -= 147456;
    if (i < 16384){ ws[O_WG1+i]  = cvt(Wg1[i]); return; }  i -= 16384;
    if (i < 64)   { ws[O_BG1+i]  = cvt(bg1[i]); return; }  i -= 64;
    if (i < 16384){ ws[O_WG2+i]  = cvt(Wg2[i]); return; }  i -= 16384;
    if (i < 256)  { ws[O_BG2+i]  = cvt(bg2[i]); return; }  i -= 256;
    if (i < 2048) { ws[O_POOL+i] = 0.f; return; }          // pooled accum zero
}

__global__ __launch_bounds__(256) void k0_prep(
    const void* Wkc, const void* bkc, const void* Wkp1, const void* bkp1,
    const void* g1, const void* be1, const void* m1, const void* v1,
    const void* Wkp2, const void* bkp2, const void* Wdef,
    const void* Wg1, const void* bg1, const void* Wg2, const void* bg2,
    float* ws)
{
    if (ws[O_FLAG] > 0.5f)
        k0_body<float>((const float*)Wkc,(const float*)bkc,(const float*)Wkp1,(const float*)bkp1,
                       (const float*)g1,(const float*)be1,(const float*)m1,(const float*)v1,
                       (const float*)Wkp2,(const float*)bkp2,(const float*)Wdef,
                       (const float*)Wg1,(const float*)bg1,(const float*)Wg2,(const float*)bg2, ws);
    else
        k0_body<bf16>((const bf16*)Wkc,(const bf16*)bkc,(const bf16*)Wkp1,(const bf16*)bkp1,
                      (const bf16*)g1,(const bf16*)be1,(const bf16*)m1,(const bf16*)v1,
                      (const bf16*)Wkp2,(const bf16*)bkp2,(const bf16*)Wdef,
                      (const bf16*)Wg1,(const bf16*)bg1,(const bf16*)Wg2,(const bf16*)bg2, ws);
}

// ---- k0b: pack MFMA bf16 weight layouts from fp32 ws ----
__global__ __launch_bounds__(256) void k0b_pack(float* ws)
{
    unsigned short* wkcb  = (unsigned short*)(ws + O_WKCB);
    unsigned short* wkp1b = (unsigned short*)(ws + O_WKP1B);
    unsigned short* wdefb = (unsigned short*)(ws + O_WDEFB);
    int i = blockIdx.x*256 + threadIdx.x;
    if (i < 32768){                      // [kc8][cout128][cil32] <- Wkc[cout][256]
        int kc = i>>12, cout = (i>>5)&127, cil = i&31;
        wkcb[i] = f2bu(ws[O_WKC + (size_t)cout*256 + kc*32 + cil]);
        return;
    } i -= 32768;
    if (i < 73728){                      // [ch4][kp9][cout64][cil32] <- Wkp1[cout][128][9]
        int ch = i/18432, r = i - ch*18432;
        int kp = r>>11, cout = (r>>5)&63, cil = r&31;
        wkp1b[i] = f2bu(ws[O_WKP1 + ((size_t)cout*128 + ch*32 + cil)*9 + kp]);
        return;
    } i -= 73728;
    if (i < 147456){                     // [g4][ch2][kp9][cout64][cil32] <- Wdef[g*64+cout][64][9]
        int g = i/36864, r1 = i - g*36864;
        int ch = r1/18432, r2 = r1 - ch*18432;
        int kp = r2>>11, cout = (r2>>5)&63, cil = r2&31;
        wdefb[i] = f2bu(ws[O_WDEF + (((size_t)(g*64+cout))*64 + ch*32 + cil)*9 + kp]);
    }
}

// ---- xcvt: x (NCHW fp32/bf16) -> xbt (NHWC bf16) via LDS transpose ----
template<typename T>
__device__ __forceinline__ void xcvt_body(const T* __restrict__ x, unsigned short* __restrict__ xbt,
                                          float* lT)
{
    const int b = blockIdx.y;
    const int ci0 = (blockIdx.x & 3) * 64;
    const int pos0 = (blockIdx.x >> 2) * 64;
    const int lane = threadIdx.x & 63;
    const int wrow = threadIdx.x >> 6;
    for (int i = wrow; i < 64; i += 4)
        lT[i*65 + lane] = cvt(x[((size_t)(b*256 + ci0 + i))*4096 + pos0 + lane]);
    __syncthreads();
    // packed dword writes: unit u -> pos pr (0..63), ci pair pc (0..31)
    for (int u = threadIdx.x; u < 2048; u += 256){
        const int pr = u >> 5, pc = u & 31;
        unsigned lo = f2bu(lT[(2*pc)*65 + pr]);
        unsigned hi = f2bu(lT[(2*pc+1)*65 + pr]);
        *(unsigned*)&xbt[((size_t)(b*4096) + pos0 + pr)*256 + ci0 + 2*pc] = lo | (hi<<16);
    }
}

__global__ __launch_bounds__(256) void xcvt(const void* x, unsigned short* xbt, const float* flag)
{
    __shared__ float lT[64*65];
    if (*flag > 0.5f) xcvt_body<float>((const float*)x, xbt, lT);
    else              xcvt_body<bf16>((const bf16*)x, xbt, lT);
}

// ---- k1: 1x1 conv as MFMA GEMM: [128 cout] x [256 ci] x [pos] -> compb NHWC bf16 ----
__global__ __launch_bounds__(256) void k1_mfma(
    const unsigned short* __restrict__ xbt, const unsigned short* __restrict__ wb,
    const float* __restrict__ bias, unsigned short* __restrict__ compb)
{
    __shared__ __align__(16) short lA[128*32];
    __shared__ __align__(16) short lB[128*32];
    const int b = blockIdx.y, pos0 = blockIdx.x*128;
    const int tid = threadIdx.x;
    const int wave = tid>>6, lane = tid&63, q = lane>>4, r16 = lane&15;
    const int mh = (wave&1)*64, nh = (wave>>1)*64;
    floatx4 zero = {0.f,0.f,0.f,0.f};
    floatx4 acc[4][4];
    #pragma unroll
    for (int m=0;m<4;m++){ acc[m][0]=zero; acc[m][1]=zero; acc[m][2]=zero; acc[m][3]=zero; }

    for (int kc=0;kc<8;kc++){
        __syncthreads();
        {   // stage A (weights): contiguous 4096 shorts, swizzled rows
            const short8* s = (const short8*)(wb + kc*4096);
            const int u0 = tid, u1 = tid + 256;
            *(short8*)&lA[swz8(u0>>2, u0&3)] = s[u0];
            *(short8*)&lA[swz8(u1>>2, u1&3)] = s[u1];
        }
        {   // stage B (x): [pos128][ci32] — vector 16B units, swizzled
            #pragma unroll
            for (int k=0;k<2;k++){
                const int u = tid + k*256;
                const int p = u>>2, part = u&3;
                *(short8*)&lB[swz8(p, part)] =
                    *(const short8*)(xbt + ((size_t)(b*4096)+pos0+p)*256 + kc*32 + part*8);
            }
        }
        __syncthreads();
        short8 af[4], bfr[4];
        #pragma unroll
        for (int mt=0;mt<4;mt++) af[mt]  = *(const short8*)&lA[swz8(mh + mt*16 + r16, q)];
        #pragma unroll
        for (int nt=0;nt<4;nt++) bfr[nt] = *(const short8*)&lB[swz8(nh + nt*16 + r16, q)];
        #pragma unroll
        for (int mt=0;mt<4;mt++)
            #pragma unroll
            for (int nt=0;nt<4;nt++)
                acc[mt][nt] = mfma16(af[mt], bfr[nt], acc[mt][nt]);
    }
    #pragma unroll
    for (int mt=0;mt<4;mt++){
        const int cb = mh + mt*16 + q*4;
        const float b0=bias[cb], b1=bias[cb+1], b2=bias[cb+2], b3=bias[cb+3];
        #pragma unroll
        for (int nt=0;nt<4;nt++){
            const int pos = pos0 + nh + nt*16 + r16;
            floatx4 v = acc[mt][nt];
            uint2 pk;
            pk.x = (unsigned)f2bu(v.x+b0) | ((unsigned)f2bu(v.y+b1)<<16);
            pk.y = (unsigned)f2bu(v.z+b2) | ((unsigned)f2bu(v.w+b3)<<16);
            *(uint2*)(compb + ((size_t)(b*4096)+pos)*128 + cb) = pk;
        }
    }
}

// ---- merged 3x3 convs as MFMA 9-shift GEMM.
// z=0: kernel-predictor conv (src=compb, CITOT=128, CICH=4) -> BN+SiLU -> tb (bf16 NHWC[64])
// z=1..4: grouped deform conv g=z-1 (src=xbt, CITOT=256, CICH=2) -> enh fp32 NCHW
__global__ __launch_bounds__(256) void conv3x3_all(
    const unsigned short* __restrict__ xbt, const unsigned short* __restrict__ compb,
    const unsigned short* __restrict__ wkp1b, const unsigned short* __restrict__ wdefb,
    const float* __restrict__ alpha, const float* __restrict__ beta,
    unsigned short* __restrict__ tb, float* __restrict__ enh)
{
    __shared__ __align__(16) short lX[6*66*32];   // [r][c][ci] spatial-padded, swizzled
    __shared__ __align__(16) short lW[9*64*32];   // [kp][cout][ci], swizzled
    const int row0 = blockIdx.x*4, b = blockIdx.y, z = blockIdx.z;
    const bool isKP = (z == 0);
    const int g = isKP ? 0 : (z-1);
    const int CICH  = isKP ? 4 : 2;
    const int CITOT = isKP ? 128 : 256;
    const int cibase = g*64;                       // 0 for kp branch
    const unsigned short* src  = isKP ? compb : xbt;
    const unsigned short* wsrc = isKP ? wkp1b : (wdefb + (size_t)g*36864);
    const int tid = threadIdx.x;
    const int wave = tid>>6, lane = tid&63, q = lane>>4, r16 = lane&15;
    floatx4 zero = {0.f,0.f,0.f,0.f};
    floatx4 acc[4][4];
    #pragma unroll
    for (int m=0;m<4;m++){ acc[m][0]=zero; acc[m][1]=zero; acc[m][2]=zero; acc[m][3]=zero; }

    // zero lX once (borders + out-of-range rows stay zero through all ch)
    {
        short8 zz = {0,0,0,0,0,0,0,0};
        short8* d = (short8*)lX;
        for (int i = tid; i < 1584; i += 256) d[i] = zz;
    }

    for (int ch = 0; ch < CICH; ch++){
        __syncthreads();
        {   // stage W chunk: contiguous 18432 shorts (2304 x 16B), swizzled
            const short8* s = (const short8*)(wsrc + ch*18432);
            #pragma unroll
            for (int i=0;i<9;i++){
                const int u = tid + i*256;
                *(short8*)&lW[swz8(u>>2, u&3)] = s[u];
            }
        }
        {   // stage X interior: row r valid cols 0..63 -> lX cols 1..64, swizzled
            const int gc = tid>>2, part = tid&3;
            #pragma unroll
            for (int r=0;r<6;r++){
                const int gr = row0 - 1 + r;
                if ((unsigned)gr < 64u){
                    const unsigned short* sp = src +
                        ((size_t)(b*4096) + gr*64 + gc)*CITOT + cibase + ch*32 + part*8;
                    *(short8*)&lX[swz8(r*66 + 1 + gc, part)] = *(const short8*)sp;
                }
            }
        }
        __syncthreads();
        #pragma unroll
        for (int kp=0; kp<9; kp++){
            const int dr = kp/3, dc = kp - dr*3;
            short8 af[4], bfr[4];
            #pragma unroll
            for (int mt=0;mt<4;mt++)
                af[mt] = *(const short8*)&lW[swz8(kp*64 + mt*16 + r16, q)];
            #pragma unroll
            for (int nt=0;nt<4;nt++)
                bfr[nt] = *(const short8*)&lX[swz8((wave+dr)*66 + nt*16 + r16 + dc, q)];
            #pragma unroll
            for (int mt=0;mt<4;mt++)
                #pragma unroll
                for (int nt=0;nt<4;nt++)
                    acc[mt][nt] = mfma16(af[mt], bfr[nt], acc[mt][nt]);
        }
    }
    const int orow = row0 + wave;
    if (isKP){
        #pragma unroll
        for (int mt=0;mt<4;mt++){
            const int cb = mt*16 + q*4;
            const float a0=alpha[cb],a1=alpha[cb+1],a2=alpha[cb+2],a3=alpha[cb+3];
            const float e0=beta[cb],e1=beta[cb+1],e2=beta[cb+2],e3=beta[cb+3];
            #pragma unroll
            for (int nt=0;nt<4;nt++){
                const int pos = orow*64 + nt*16 + r16;
                floatx4 v = acc[mt][nt];
                float z0=v.x*a0+e0, z1=v.y*a1+e1, z2=v.z*a2+e2, z3=v.w*a3+e3;
                z0 = z0/(1.f+expf(-z0)); z1 = z1/(1.f+expf(-z1));
                z2 = z2/(1.f+expf(-z2)); z3 = z3/(1.f+expf(-z3));
                uint2 pk;
                pk.x = (unsigned)f2bu(z0) | ((unsigned)f2bu(z1)<<16);
                pk.y = (unsigned)f2bu(z2) | ((unsigned)f2bu(z3)<<16);
                *(uint2*)(tb + ((size_t)(b*4096)+pos)*64 + cb) = pk;
            }
        }
    } else {
        #pragma unroll
        for (int mt=0;mt<4;mt++){
            #pragma unroll
            for (int nt=0;nt<4;nt++){
                const int pos = orow*64 + nt*16 + r16;
                floatx4 v = acc[mt][nt];
                float* op = enh + ((size_t)(b*256) + g*64 + mt*16 + q*4)*4096 + pos;
                op[0]=v.x; op[4096]=v.y; op[8192]=v.z; op[12288]=v.w;
            }
        }
    }
}

// ---- k3: 1x1 conv t(64)->36 + softmax over groups of 9 (NHWC bf16 input) ----
__global__ __launch_bounds__(128) void k3_kpred(
    const unsigned short* __restrict__ tb, const float* __restrict__ W,
    const float* __restrict__ bias, float* __restrict__ kw)
{
    __shared__ float wl[2304];
    __shared__ float bl[36];
    for (int i=threadIdx.x;i<2304;i+=128) wl[i]=W[i];
    if (threadIdx.x<36) bl[threadIdx.x]=bias[threadIdx.x];
    __syncthreads();
    const int gid = blockIdx.x*128 + threadIdx.x;    // b*4096+pos
    const unsigned short* tp = tb + (size_t)gid*64;
    float acc[36];
    #pragma unroll
    for (int o=0;o<36;o++) acc[o]=bl[o];
    #pragma unroll
    for (int c8=0;c8<8;c8++){
        uint4 pk = *(const uint4*)(tp + c8*8);
        unsigned u[4] = {pk.x, pk.y, pk.z, pk.w};
        float f[8];
        #pragma unroll
        for (int j=0;j<4;j++){
            f[2*j]   = bu2f((unsigned short)(u[j]&0xFFFFu));
            f[2*j+1] = bu2f((unsigned short)(u[j]>>16));
        }
        #pragma unroll
        for (int jj=0;jj<8;jj++){
            const int ci = c8*8+jj;
            #pragma unroll
            for (int o=0;o<36;o++) acc[o] += f[jj]*wl[o*64+ci];
        }
    }
    float* op = kw + (size_t)gid*36;
    #pragma unroll
    for (int s=0;s<4;s++){
        float mx = acc[s*9];
        #pragma unroll
        for (int k=1;k<9;k++) mx = fmaxf(mx, acc[s*9+k]);
        float e[9]; float sum=0.f;
        #pragma unroll
        for (int k=0;k<9;k++){ e[k]=expf(acc[s*9+k]-mx); sum+=e[k]; }
        float inv = 1.f/sum;
        #pragma unroll
        for (int k=0;k<9;k++) op[s*9+k] = e[k]*inv;
    }
}

// ---- k5: reassembly + bilinear upsample add -> out (fp32), fused spatial-sum ----
// lane owns source-col pair (2a,2a+1); half-wave owns one channel.
// x stencil: 3 unaligned 4-wide loads; enh: float2+scalar; stores: float2.
template<typename T>
__device__ __forceinline__ void k5_body(
    const T* __restrict__ x, const float* __restrict__ kw,
    const float* __restrict__ enh, float* __restrict__ out,
    float* __restrict__ pooled, float* kwl)
{
    const int hi = blockIdx.x & 63;
    const int b  = blockIdx.x >> 6;
    const int c0 = blockIdx.y * 64;
    for (int i=threadIdx.x;i<2304;i+=256){
        int wi = i/36, r = i - wi*36;
        kwl[wi*37+r] = kw[((size_t)(b*4096 + hi*64 + wi))*36 + r];
    }
    __syncthreads();
    const int lane = threadIdx.x & 63;
    const int wv   = threadIdx.x >> 6;
    const int a    = lane & 31;
    const int hsel = lane >> 5;

    float k0r[36], k1r[36];
    #pragma unroll
    for (int r=0;r<36;r++) k0r[r] = kwl[(2*a)*37+r];
    #pragma unroll
    for (int r=0;r<36;r++) k1r[r] = kwl[(2*a+1)*37+r];

    const bool vy0 = hi>0, vy2 = hi<63;
    const int rm = vy0? hi-1 : 0;
    const int rp = vy2? hi+1 : 63;
    const int y0 = hi*2;
    const bool e0 = (a==0), e31 = (a==31);
    const int xb = e0 ? 0 : (e31 ? 60 : (2*a-1));   // x 4-wide load base col
    const int eAb = e0 ? 0 : a-1;                   // enh A float2 base (a-1,a)
    const int eBb = 31 + a;                         // enh B float2 base (31+a,32+a)
    const int eAr = a+1;                            // enh A right col
    const int eBr = e31 ? 63 : 33+a;                // enh B right col (clamped)

    for (int it=0; it<8; ++it){
        const int c = c0 + (wv<<1) + hsel + (it<<3);
        const T* xc = x + ((size_t)(b*256)+c)*4096 + hi*64 + xb;
        // 3 stencil rows, 4-wide; uniform-branch zero for invalid rows
        float g[3][4];
        ld4(xc, g[1][0], g[1][1], g[1][2], g[1][3]);
        if (vy0) ld4(xc-64, g[0][0], g[0][1], g[0][2], g[0][3]);
        else     { g[0][0]=0.f; g[0][1]=0.f; g[0][2]=0.f; g[0][3]=0.f; }
        if (vy2) ld4(xc+64, g[2][0], g[2][1], g[2][2], g[2][3]);
        else     { g[2][0]=0.f; g[2][1]=0.f; g[2][2]=0.f; g[2][3]=0.f; }
        // per-row stencil values: s0=(xl0,xc0,xr0), s1=(xc0,xr0,xr1)
        float w0[3][4];
        #pragma unroll
        for (int i=0;i<3;i++){
            float g0=g[i][0], g1=g[i][1], g2=g[i][2], g3=g[i][3];
            w0[i][0] = e0 ? 0.f : (e31 ? g1 : g0);
            w0[i][1] = e0 ? g0  : (e31 ? g2 : g1);
            w0[i][2] = e0 ? g1  : (e31 ? g3 : g2);
            w0[i][3] = e0 ? g2  : (e31 ? 0.f : g3);
        }
        float ko[2][4];
        #pragma unroll
        for (int s=0;s<4;s++){
            float a0c = 0.f, a1c = 0.f;
            #pragma unroll
            for (int i=0;i<3;i++){
                a0c += w0[i][0]*k0r[s*9+3*i] + w0[i][1]*k0r[s*9+3*i+1] + w0[i][2]*k0r[s*9+3*i+2];
                a1c += w0[i][1]*k1r[s*9+3*i] + w0[i][2]*k1r[s*9+3*i+1] + w0[i][3]*k1r[s*9+3*i+2];
            }
            ko[0][s]=a0c; ko[1][s]=a1c;
        }
        // upsample: horizontal interpolation per enh row, then vertical
        const float* ec = enh + ((size_t)(b*256)+c)*4096;
        float hAe[3], hAo[3], hBe[3], hBo[3];
        const int rows[3] = {rm, hi, rp};
        #pragma unroll
        for (int i=0;i<3;i++){
            const float* er = ec + rows[i]*64;
            float fA0, fA1; ld2f(er + eAb, fA0, fA1);
            float vAl = fA0, vAc = e0 ? fA0 : fA1;
            float vAr = er[eAr];
            float fB0, fB1; ld2f(er + eBb, fB0, fB1);
            float vBr = er[eBr];
            hAe[i] = 0.25f*vAl + 0.75f*vAc;
            hAo[i] = 0.75f*vAc + 0.25f*vAr;
            hBe[i] = 0.25f*fB0 + 0.75f*fB1;
            hBo[i] = 0.75f*fB1 + 0.25f*vBr;
        }
        float uAe0 = 0.25f*hAe[0] + 0.75f*hAe[1], uAe1 = 0.75f*hAe[1] + 0.25f*hAe[2];
        float uAo0 = 0.25f*hAo[0] + 0.75f*hAo[1], uAo1 = 0.75f*hAo[1] + 0.25f*hAo[2];
        float uBe0 = 0.25f*hBe[0] + 0.75f*hBe[1], uBe1 = 0.75f*hBe[1] + 0.25f*hBe[2];
        float uBo0 = 0.25f*hBo[0] + 0.75f*hBo[1], uBo1 = 0.75f*hBo[1] + 0.25f*hBo[2];
        // outputs: rows y0,y0+1; cols 2a,2a+1 (A) and 64+2a,64+2a+1 (B)
        float o00 = ko[0][0]+uAe0, o01 = ko[1][0]+uAo0;
        float o02 = ko[0][1]+uBe0, o03 = ko[1][1]+uBo0;
        float o10 = ko[0][2]+uAe1, o11 = ko[1][2]+uAo1;
        float o12 = ko[0][3]+uBe1, o13 = ko[1][3]+uBo1;
        float* o = out + (((size_t)(b*256)+c)*128 + y0)*128;
        *(float2*)(o + 2*a)        = make_float2(o00, o01);
        *(float2*)(o + 64 + 2*a)   = make_float2(o02, o03);
        *(float2*)(o + 128 + 2*a)  = make_float2(o10, o11);
        *(float2*)(o + 192 + 2*a)  = make_float2(o12, o13);
        // pool partial: half-wave (32 lanes) covers all 256 outputs of (c, row-pair)
        float ps = (o00+o01) + (o02+o03) + (o10+o11) + (o12+o13);
        ps += __shfl_down(ps,16,32); ps += __shfl_down(ps, 8,32);
        ps += __shfl_down(ps, 4,32); ps += __shfl_down(ps, 2,32);
        ps += __shfl_down(ps, 1,32);
        if (a==0) atomicAdd(&pooled[b*256 + c], ps);
    }
}

__global__ __launch_bounds__(256) void k5_fuse(
    const void* x, const float* kw, const float* enh, float* out,
    float* pooled, const float* flag)
{
    __shared__ float kwl[64*37];
    if (*flag > 0.5f) k5_body<float>((const float*)x, kw, enh, out, pooled, kwl);
    else              k5_body<bf16>((const bf16*)x, kw, enh, out, pooled, kwl);
}

// ---- k7: SE gate (pooled holds spatial SUM; scale by 1/16384) ----
__global__ __launch_bounds__(256) void k7_gate(
    const float* __restrict__ pooled,
    const float* __restrict__ Wg1, const float* __restrict__ bg1,
    const float* __restrict__ Wg2, const float* __restrict__ bg2,
    float* __restrict__ gate)
{
    const int b = blockIdx.x;
    __shared__ float pl[256];
    __shared__ float hid[64];
    pl[threadIdx.x] = pooled[b*256+threadIdx.x] * (1.f/16384.f);
    __syncthreads();
    if (threadIdx.x < 64){
        float a = bg1[threadIdx.x];
        const float* w = Wg1 + (size_t)threadIdx.x*256;
        for (int c=0;c<256;c++) a += w[c]*pl[c];
        hid[threadIdx.x] = a/(1.f+expf(-a));
    }
    __syncthreads();
    float a = bg2[threadIdx.x];
    const float* w = Wg2 + (size_t)threadIdx.x*64;
    for (int j=0;j<64;j++) a += w[j]*hid[j];
    gate[b*256+threadIdx.x] = 1.f/(1.f+expf(-a));
}

// ---- k8: out *= gate ----
__global__ __launch_bounds__(256) void k8_scale(
    float* __restrict__ out, const float* __restrict__ gate)
{
    const size_t gid = (size_t)blockIdx.x*256 + threadIdx.x;
    const float g = gate[gid>>12];
    float4* p = (float4*)out;
    float4 v = p[gid];
    v.x*=g; v.y*=g; v.z*=g; v.w*=g;
    p[gid] = v;
}

extern "C" void kernel_launch(void* const* d_in, const int* in_sizes, int n_in,
                              void* d_out, int out_size, void* d_ws, size_t ws_size,
                              hipStream_t stream)
{
    float* ws = (float*)d_ws;
    float* out = (float*)d_out;
    unsigned short* xbt   = (unsigned short*)(ws + O_XBT);
    unsigned short* compb = (unsigned short*)(ws + O_COMPB);
    unsigned short* tb    = (unsigned short*)(ws + O_TB);
    unsigned short* wkcb  = (unsigned short*)(ws + O_WKCB);
    unsigned short* wkp1b = (unsigned short*)(ws + O_WKP1B);
    unsigned short* wdefb = (unsigned short*)(ws + O_WDEFB);

    kdet<<<1, 256, 0, stream>>>((const unsigned*)d_in[1], ws + O_FLAG);
    k0_prep<<<1140, 256, 0, stream>>>(d_in[1],d_in[2],d_in[3],d_in[4],d_in[5],d_in[6],d_in[7],d_in[8],
                                      d_in[9],d_in[10],d_in[11],d_in[12],d_in[13],d_in[14],d_in[15], ws);
    k0b_pack<<<992, 256, 0, stream>>>(ws);
    xcvt<<<dim3(256,8), 256, 0, stream>>>(d_in[0], xbt, ws+O_FLAG);
    k1_mfma<<<dim3(32,8), 256, 0, stream>>>(xbt, wkcb, ws+O_BKC, compb);
    conv3x3_all<<<dim3(16,8,5), 256, 0, stream>>>(xbt, compb, wkp1b, wdefb,
                                                  ws+O_ALPHA, ws+O_BETA, tb, ws+O_ENH);
    k3_kpred<<<256, 128, 0, stream>>>(tb, ws+O_WKP2, ws+O_BKP2, ws+O_KW);
    k5_fuse<<<dim3(512,4), 256, 0, stream>>>(d_in[0], ws+O_KW, ws+O_ENH, out, ws+O_POOL, ws+O_FLAG);
    k7_gate<<<8, 256, 0, stream>>>(ws+O_POOL, ws+O_WG1, ws+O_BG1, ws+O_WG2, ws+O_BG2, ws+O_GATE);
    k8_scale<<<32768, 256, 0, stream>>>(out, ws+O_GATE);
}